// Round 1
// baseline (220.408 us; speedup 1.0000x reference)
//
#include <hip/hip_runtime.h>

typedef __bf16 bf16;
typedef __attribute__((ext_vector_type(8))) __bf16 bf16x8;
typedef __attribute__((ext_vector_type(4))) __bf16 bf16x4;
typedef __attribute__((ext_vector_type(4))) float f32x4;

// ---------------------------------------------------------------------------
// async global->LDS, 16B per lane, 1024B per wave-call.
// LDS dest is wave-uniform base + lane*16 (hardware-enforced).
// ---------------------------------------------------------------------------
__device__ __forceinline__ void gload16(const void* g, void* l) {
  __builtin_amdgcn_global_load_lds(
      (__attribute__((address_space(1))) void*)(g),
      (__attribute__((address_space(3))) void*)(l), 16, 0, 0);
}

// ---------------------------------------------------------------------------
// Workspace layout (bytes):
//   xh  : NHWC padded input, bf16 [130][130][512]        = 17,305,600
//   w1t : conv1 weights,     bf16 [9][512 oc][512 c]     =  4,718,592
//   w2p : packed head wts,   bf16 [80 oc2][512 c]        =     81,920
//   mid : conv1 output NHWC, bf16 [16384 px][512 oc]     = 16,777,216
// total = 38,883,328 B
// ---------------------------------------------------------------------------
#define WS_XH   0
#define WS_W1T  17305600
#define WS_W2P  22024192
#define WS_MID  22106112

// d_out layout (fp32): loc[196608*4] | cls[196608*2] | roi[196608*4]
#define OUT_CLS 786432
#define OUT_ROI 1179648

// ---------------- prep: zero padded xh (16B stores) ----------------
__global__ void zero_xh(int4* __restrict__ p) {
  p[blockIdx.x * 256 + threadIdx.x] = make_int4(0, 0, 0, 0);
}

// ---------------- prep: NCHW fp32 -> NHWC bf16 interior transpose ----------
// block: one image row r (1..128), 64-col tile, 64-channel tile. 128*2*8=2048 blocks
__global__ void transpose_x(const float* __restrict__ x, bf16* __restrict__ xh) {
  __shared__ float lds[64][65];   // +1 pad: conflict-free both phases
  const int tid  = threadIdx.x;
  const int ct   = blockIdx.x & 7;          // channel tile (8)
  const int colt = (blockIdx.x >> 3) & 1;   // col tile (2)
  const int r    = 1 + (blockIdx.x >> 4);   // padded row 1..128
  const int c0   = ct * 64;
  const int col0 = 1 + colt * 64;
  const int lcol = tid & 63;
  const int coff = tid >> 6;
#pragma unroll
  for (int i = 0; i < 16; ++i) {
    const int cl = coff + i * 4;
    lds[cl][lcol] = x[(long)(c0 + cl) * 16384 + (r - 1) * 128 + (col0 - 1) + lcol];
  }
  __syncthreads();
#pragma unroll
  for (int i = 0; i < 16; ++i) {
    const int coll = coff + i * 4;
    xh[(long)(r * 130 + col0 + coll) * 512 + c0 + lcol] = (bf16)lds[lcol][coll];
  }
}

// ---------------- prep: conv1_w [oc][c][3][3] fp32 -> w1t [j][oc][c] bf16 ---
__global__ void prep_w1(const float* __restrict__ w1, bf16* __restrict__ w1t) {
  const int idx = blockIdx.x * 256 + threadIdx.x;   // 9*512*512 = 2359296
  const int c  = idx & 511;
  const int oc = (idx >> 9) & 511;
  const int j  = idx >> 18;
  w1t[idx] = (bf16)w1[(long)(oc * 512 + c) * 9 + j];
}

// ---------------- prep: pack loc_w(48)+score_w(24)+zeros(8) -> w2p[80][512] -
__global__ void prep_w2(const float* __restrict__ loc_w,
                        const float* __restrict__ score_w,
                        bf16* __restrict__ w2p) {
  const int idx = blockIdx.x * 256 + threadIdx.x;   // 80*512 = 40960
  const int c  = idx & 511;
  const int oc = idx >> 9;
  float v = 0.f;
  if (oc < 48)      v = loc_w[oc * 512 + c];
  else if (oc < 72) v = score_w[(oc - 48) * 512 + c];
  w2p[idx] = (bf16)v;
}

// ---------------- conv1 implicit GEMM (m97 structure) ----------------------
// C[oc,px] = sum_{j,c} w1t[j][oc][c] * xh[(h+ky)*130 + (w+kx)][c]
// grid: 512 blocks = 4 oc-tiles x 128 px-rows. block = 256 thr (4 waves).
// per block: 128 oc x 128 px, K-loop = 9 offsets x 16 chunks of BK=32.
__global__ __launch_bounds__(256, 2) void conv1_gemm(
    const bf16* __restrict__ w1t, const bf16* __restrict__ xh,
    const float* __restrict__ b1, bf16* __restrict__ mid) {
  __shared__ bf16 ldsA[128 * 32];   // [oc][c] rows of 64B
  __shared__ bf16 ldsB[128 * 32];   // [px][c] rows of 64B
  const int tid  = threadIdx.x;
  const int wave = tid >> 6;
  const int lane = tid & 63;
  const int quad = lane >> 4;
  const int l15  = lane & 15;
  const int wr = wave >> 1, wc = wave & 1;      // 2x2 wave grid (64x64 each)
  const int oc_tile = blockIdx.x & 3;
  const int h       = blockIdx.x >> 2;          // image row
  const char* w1tB = (const char*)w1t + (long)oc_tile * 128 * 1024;
  const char* xhB  = (const char*)xh;
  const int srow  = lane >> 2;        // staging: 16 rows per call, 4 lanes/row
  const int sbyte = (lane & 3) * 16;

  f32x4 acc[4][4];
#pragma unroll
  for (int i = 0; i < 4; ++i)
#pragma unroll
    for (int k = 0; k < 4; ++k) acc[i][k] = (f32x4){0.f, 0.f, 0.f, 0.f};

  for (int j = 0; j < 9; ++j) {
    const int ky = j / 3, kx = j - ky * 3;
    const char* aBase = w1tB + (long)j * 524288;
    const char* bBase = xhB + (long)((h + ky) * 130 + kx) * 1024;
    for (int ck = 0; ck < 16; ++ck) {
      const int c0b = ck * 64;
      __syncthreads();   // previous iter's LDS reads complete
#pragma unroll
      for (int call = 0; call < 2; ++call) {
        const int row = wave * 32 + call * 16;
        gload16(aBase + (long)(row + srow) * 1024 + c0b + sbyte,
                (char*)ldsA + row * 64);
        gload16(bBase + (long)(row + srow) * 1024 + c0b + sbyte,
                (char*)ldsB + row * 64);
      }
      __syncthreads();   // drains vmcnt(0): staged tiles visible
      bf16x8 af[4], bfr[4];
#pragma unroll
      for (int mi = 0; mi < 4; ++mi)
        af[mi] = *(const bf16x8*)&ldsA[(wr * 64 + mi * 16 + l15) * 32 + quad * 8];
#pragma unroll
      for (int ni = 0; ni < 4; ++ni)
        bfr[ni] = *(const bf16x8*)&ldsB[(wc * 64 + ni * 16 + l15) * 32 + quad * 8];
#pragma unroll
      for (int mi = 0; mi < 4; ++mi)
#pragma unroll
        for (int ni = 0; ni < 4; ++ni)
          acc[mi][ni] = __builtin_amdgcn_mfma_f32_16x16x32_bf16(
              af[mi], bfr[ni], acc[mi][ni], 0, 0, 0);
    }
  }

  // epilogue: bias + relu, store bf16 NHWC mid[px][oc] (4 consecutive oc = 8B)
#pragma unroll
  for (int mi = 0; mi < 4; ++mi) {
    const int oc = oc_tile * 128 + wr * 64 + mi * 16 + quad * 4;
    const float bv0 = b1[oc], bv1 = b1[oc + 1], bv2 = b1[oc + 2], bv3 = b1[oc + 3];
#pragma unroll
    for (int ni = 0; ni < 4; ++ni) {
      const int px = wc * 64 + ni * 16 + l15;
      f32x4 a = acc[mi][ni];
      float t0 = a[0] + bv0; t0 = t0 > 0.f ? t0 : 0.f;
      float t1 = a[1] + bv1; t1 = t1 > 0.f ? t1 : 0.f;
      float t2 = a[2] + bv2; t2 = t2 > 0.f ? t2 : 0.f;
      float t3 = a[3] + bv3; t3 = t3 > 0.f ? t3 : 0.f;
      bf16x4 v = {(bf16)t0, (bf16)t1, (bf16)t2, (bf16)t3};
      *(bf16x4*)(mid + (long)(h * 128 + px) * 512 + oc) = v;
    }
  }
}

// ---------------- head: 1x1 convs as GEMM + anchor-decode epilogue ---------
// C[oc2,px] = sum_c w2p[oc2][c] * mid[px][c].  M=80, K=512, N=16384.
// grid: 256 blocks x 64 px. wave w handles px sub-tile [w*16, w*16+16).
__global__ __launch_bounds__(256) void head_gemm(
    const bf16* __restrict__ w2p, const bf16* __restrict__ mid,
    const float* __restrict__ loc_b, const float* __restrict__ score_b,
    float* __restrict__ out) {
  __shared__ bf16 ldsA[80 * 32];   // [oc2][c]
  __shared__ bf16 ldsB[64 * 32];   // [px][c]
  const int tid  = threadIdx.x;
  const int wave = tid >> 6;
  const int lane = tid & 63;
  const int quad = lane >> 4;
  const int l15  = lane & 15;
  const int px0  = blockIdx.x * 64;
  const char* wB = (const char*)w2p;
  const char* mB = (const char*)mid + (long)px0 * 1024;
  const int srow  = lane >> 2;
  const int sbyte = (lane & 3) * 16;

  f32x4 acc[5];
#pragma unroll
  for (int i = 0; i < 5; ++i) acc[i] = (f32x4){0.f, 0.f, 0.f, 0.f};

  for (int st = 0; st < 16; ++st) {
    const int c0b = st * 64;
    __syncthreads();
    // A tile 80x32 = 5 calls (wave w takes call w; wave 0 also call 4)
    gload16(wB + (long)(wave * 16 + srow) * 1024 + c0b + sbyte,
            (char*)ldsA + wave * 1024);
    if (wave == 0)
      gload16(wB + (long)(64 + srow) * 1024 + c0b + sbyte, (char*)ldsA + 4096);
    // B tile 64x32 = 4 calls
    gload16(mB + (long)(wave * 16 + srow) * 1024 + c0b + sbyte,
            (char*)ldsB + wave * 1024);
    __syncthreads();
    bf16x8 bfr = *(const bf16x8*)&ldsB[(wave * 16 + l15) * 32 + quad * 8];
#pragma unroll
    for (int mi = 0; mi < 5; ++mi) {
      bf16x8 af = *(const bf16x8*)&ldsA[(mi * 16 + l15) * 32 + quad * 8];
      acc[mi] = __builtin_amdgcn_mfma_f32_16x16x32_bf16(af, bfr, acc[mi], 0, 0, 0);
    }
  }

  // epilogue. D row = oc2 = mi*16 + quad*4 + r; col px = l15.
  const int p    = px0 + wave * 16 + l15;
  const int hh   = p >> 7;        // spatial row
  const int wcol = p & 127;       // spatial col
  const float cx = 16.f * (float)hh;     // transposed-anchor convention
  const float cy = 16.f * (float)wcol;
  // anchor half-sizes: a = mi*4 + quad; aw = S[ratio][size], size idx = quad
  const float s0 = quad == 0 ? 45.f : quad == 1 ? 91.f : quad == 2 ? 181.f : 362.f;
  const float s1 = quad == 0 ? 32.f : quad == 1 ? 64.f : quad == 2 ? 128.f : 256.f;
  const float s2 = quad == 0 ? 23.f : quad == 1 ? 45.f : quad == 2 ? 91.f : 181.f;
  const float aw[3] = {s0, s1, s2};
  const float ah[3] = {s2, s1, s0};
#pragma unroll
  for (int mi = 0; mi < 5; ++mi) {
#pragma unroll
    for (int r = 0; r < 4; ++r) {
      const int oc2 = mi * 16 + quad * 4 + r;
      float v = acc[mi][r];
      if (mi < 3) {                       // oc2 < 48: loc channel
        v += loc_b[oc2];
        out[p * 48 + oc2] = v;
        float roi;
        if (r == 0)      roi = v * aw[mi] + cx;
        else if (r == 1) roi = v * ah[mi] + cy;
        else if (r == 2) roi = __expf(v) * aw[mi];
        else             roi = __expf(v) * ah[mi];
        out[OUT_ROI + p * 48 + oc2] = roi;
      } else {
        const int sc = oc2 - 48;
        if (sc < 24) {                    // score channel (72..79 = pad, drop)
          v += score_b[sc];
          out[OUT_CLS + p * 24 + sc] = v;
        }
      }
    }
  }
}

// ---------------------------------------------------------------------------
extern "C" void kernel_launch(void* const* d_in, const int* in_sizes, int n_in,
                              void* d_out, int out_size, void* d_ws, size_t ws_size,
                              hipStream_t stream) {
  (void)in_sizes; (void)n_in; (void)out_size; (void)ws_size;
  const float* x       = (const float*)d_in[0];
  const float* conv1_w = (const float*)d_in[1];
  const float* conv1_b = (const float*)d_in[2];
  const float* score_w = (const float*)d_in[3];
  const float* score_b = (const float*)d_in[4];
  const float* loc_w   = (const float*)d_in[5];
  const float* loc_b   = (const float*)d_in[6];
  char* ws = (char*)d_ws;
  bf16* xh  = (bf16*)(ws + WS_XH);
  bf16* w1t = (bf16*)(ws + WS_W1T);
  bf16* w2p = (bf16*)(ws + WS_W2P);
  bf16* mid = (bf16*)(ws + WS_MID);
  float* out = (float*)d_out;

  hipLaunchKernelGGL(zero_xh,     dim3(4225), dim3(256), 0, stream, (int4*)xh);
  hipLaunchKernelGGL(transpose_x, dim3(2048), dim3(256), 0, stream, x, xh);
  hipLaunchKernelGGL(prep_w1,     dim3(9216), dim3(256), 0, stream, conv1_w, w1t);
  hipLaunchKernelGGL(prep_w2,     dim3(160),  dim3(256), 0, stream, loc_w, score_w, w2p);
  hipLaunchKernelGGL(conv1_gemm,  dim3(512),  dim3(256), 0, stream, w1t, xh, conv1_b, mid);
  hipLaunchKernelGGL(head_gemm,   dim3(256),  dim3(256), 0, stream, w2p, mid, loc_b, score_b, out);
}